// Round 2
// baseline (571.044 us; speedup 1.0000x reference)
//
#include <hip/hip_runtime.h>
#include <hip/hip_bf16.h>

typedef unsigned short u16;
typedef __attribute__((ext_vector_type(4))) float f32x4;
typedef __attribute__((ext_vector_type(8))) short s16x8;  // 8 x bf16 (4 VGPRs)
typedef __attribute__((ext_vector_type(4))) short s16x4;

#define DEVFN static __device__ __forceinline__

DEVFN u16 f2bf(float f) {  // fp32 -> bf16, round-nearest-even
  unsigned u = __float_as_uint(f);
  return (u16)((u + 0x7fffu + ((u >> 16) & 1u)) >> 16);
}
DEVFN float bf2f(u16 h) { return __uint_as_float(((unsigned)h) << 16); }

DEVFN void gl_lds16(const void* g, void* l) {  // async global->LDS, 16B/lane
  __builtin_amdgcn_global_load_lds(
      (const __attribute__((address_space(1))) unsigned int*)g,
      (__attribute__((address_space(3))) unsigned int*)l, 16, 0, 0);
}

DEVFN f32x4 mfma16(s16x8 a, s16x8 b, f32x4 c) {
  return __builtin_amdgcn_mfma_f32_16x16x32_bf16(a, b, c, 0, 0, 0);
}

// ---------------------------------------------------------------- cvt x -> bf16
__global__ void k_cvt_x(const float4* __restrict__ x, u16* __restrict__ xb, int n4) {
  int i = blockIdx.x * 256 + threadIdx.x;
  if (i >= n4) return;
  float4 v = x[i];
  s16x4 o;
  o[0] = (short)f2bf(v.x); o[1] = (short)f2bf(v.y);
  o[2] = (short)f2bf(v.z); o[3] = (short)f2bf(v.w);
  *(s16x4*)(xb + (size_t)i * 4) = o;
}

// ------------------------------------------- transpose+convert Wq/Wk/Wv (f32 512x4096 -> bf16 4096x512)
__global__ void k_transpose_w3(const float* __restrict__ Wq, const float* __restrict__ Wk,
                               const float* __restrict__ Wv, u16* __restrict__ dst,
                               float qscale) {
  __shared__ float tile[64][65];
  const int z = blockIdx.z;
  const float* src = (z == 0) ? Wq : (z == 1) ? Wk : Wv;
  const float scale = (z == 0) ? qscale : 1.f;
  u16* d = dst + (size_t)z * 2097152;
  int k0 = blockIdx.x * 64, n0 = blockIdx.y * 64;
  int t = threadIdx.x, c = t & 63, r4 = t >> 6;
#pragma unroll
  for (int i = 0; i < 16; ++i) {
    int r = i * 4 + r4;
    tile[r][c] = src[(size_t)(k0 + r) * 4096 + n0 + c] * scale;
  }
  __syncthreads();
#pragma unroll
  for (int i = 0; i < 16; ++i) {
    int r = i * 4 + r4;
    d[(size_t)(n0 + r) * 512 + k0 + c] = f2bf(tile[c][r]);
  }
}

// ------------------------------------------- transpose+convert Wo (f32 KxN -> bf16 NxK)
__global__ void k_transpose_w(const float* __restrict__ src, u16* __restrict__ dst,
                              int K, int N, float scale) {
  __shared__ float tile[64][65];
  int k0 = blockIdx.x * 64, n0 = blockIdx.y * 64;
  int t = threadIdx.x, c = t & 63, r4 = t >> 6;
#pragma unroll
  for (int i = 0; i < 16; ++i) {
    int r = i * 4 + r4;
    tile[r][c] = src[(size_t)(k0 + r) * N + n0 + c] * scale;
  }
  __syncthreads();
#pragma unroll
  for (int i = 0; i < 16; ++i) {
    int r = i * 4 + r4;
    dst[(size_t)(n0 + r) * K + k0 + c] = f2bf(tile[c][r]);
  }
}

// ------------------------------------------- transpose V region of QKV -> Vt [32][512][1024]
__global__ void k_transpose_v(const u16* __restrict__ qkv, u16* __restrict__ vt) {
  __shared__ u16 tile[64][65];
  int bh = blockIdx.z, b = bh >> 3, h = bh & 7;
  int kk0 = blockIdx.x * 64, d0 = blockIdx.y * 64;
  int t = threadIdx.x, c = t & 63, r4 = t >> 6;
#pragma unroll
  for (int i = 0; i < 16; ++i) {
    int r = i * 4 + r4;  // key-local
    tile[r][c] = qkv[(size_t)(b * 1024 + kk0 + r) * 12288 + 8192 + h * 512 + d0 + c];
  }
  __syncthreads();
#pragma unroll
  for (int i = 0; i < 16; ++i) {
    int r = i * 4 + r4;  // d-local
    vt[(size_t)(bh * 512 + d0 + r) * 1024 + kk0 + c] = tile[c][r];
  }
}

// ---------------------------------------------------------------- m97-style GEMM
// C[M][ldc] = A[M][K] @ Bt[N][K]^T   (A, Bt bf16 row-major; B^T layout)
// EPI 0: C bf16;  EPI 1: C f32 + bias
template <int BM, int BN, int EPI>
__global__ void __launch_bounds__(256, 2) k_gemm(
    const u16* __restrict__ A, const u16* __restrict__ Bt,
    void* __restrict__ Cp, const float* __restrict__ bias,
    int M, int N, int K, int ldc) {
  constexpr int MR = BM / 32, NR = BN / 32;      // frags per wave
  constexpr int CHA = BM / 16, CHB = BN / 16;    // 1KB staging chunks
  __shared__ alignas(16) u16 Alds[BM * 32];
  __shared__ alignas(16) u16 Blds[BN * 32];
  const int tid = threadIdx.x, lane = tid & 63, wv = tid >> 6;
  const int wr = wv >> 1, wc = wv & 1;
  const int row0 = blockIdx.y * BM, col0 = blockIdx.x * BN;
  const char* Ab = (const char*)A;
  const char* Bb = (const char*)Bt;
  const f32x4 zero4 = {0.f, 0.f, 0.f, 0.f};
  f32x4 acc[MR][NR];
#pragma unroll
  for (int m = 0; m < MR; ++m)
#pragma unroll
    for (int n = 0; n < NR; ++n) acc[m][n] = zero4;

  for (int k0 = 0; k0 < K; k0 += 32) {
#pragma unroll
    for (int j = 0; j < CHA / 4; ++j) {
      int ch = j * 4 + wv;
      int r = ch * 16 + (lane >> 2);
      int cb = (lane & 3) * 16;
      gl_lds16(Ab + ((size_t)(row0 + r) * K + k0) * 2 + cb, (char*)Alds + ch * 1024);
    }
#pragma unroll
    for (int j = 0; j < CHB / 4; ++j) {
      int ch = j * 4 + wv;
      int r = ch * 16 + (lane >> 2);
      int cb = (lane & 3) * 16;
      gl_lds16(Bb + ((size_t)(col0 + r) * K + k0) * 2 + cb, (char*)Blds + ch * 1024);
    }
    __syncthreads();
    s16x8 af[MR], bfr[NR];
#pragma unroll
    for (int m = 0; m < MR; ++m)
      af[m] = *(const s16x8*)((const char*)Alds +
               (wr * (BM / 2) + m * 16 + (lane & 15)) * 64 + (lane >> 4) * 16);
#pragma unroll
    for (int n = 0; n < NR; ++n)
      bfr[n] = *(const s16x8*)((const char*)Blds +
                (wc * (BN / 2) + n * 16 + (lane & 15)) * 64 + (lane >> 4) * 16);
#pragma unroll
    for (int m = 0; m < MR; ++m)
#pragma unroll
      for (int n = 0; n < NR; ++n) acc[m][n] = mfma16(af[m], bfr[n], acc[m][n]);
    __syncthreads();
  }
#pragma unroll
  for (int m = 0; m < MR; ++m)
#pragma unroll
    for (int n = 0; n < NR; ++n)
#pragma unroll
      for (int i = 0; i < 4; ++i) {
        int r = row0 + wr * (BM / 2) + m * 16 + (lane >> 4) * 4 + i;
        int c = col0 + wc * (BN / 2) + n * 16 + (lane & 15);
        if (EPI == 0)
          ((u16*)Cp)[(size_t)r * ldc + c] = f2bf(acc[m][n][i]);
        else
          ((float*)Cp)[(size_t)r * ldc + c] = acc[m][n][i] + bias[c];
      }
}

// ---------------------------------------------------------------- flash attention
// grid 512: one 64-row q-tile per block. bh = bid&31, qt = 15-(bid>>5) (heavy first).
// 8 waves: qs = wv>>2 (32 q-rows), kg = wv&3 (16 keys in QK / 128-d slice in PV).
// Q is STREAMED from global (L1/L2-hot) each tile instead of held in registers,
// so combined regs fit 4 waves/SIMD -> 2 blocks/CU (TLP hides barrier drains).
__global__ void __launch_bounds__(512, 4) k_attn(
    const u16* __restrict__ qkv, const u16* __restrict__ vt, u16* __restrict__ O) {
  __shared__ alignas(128) unsigned char kvb[65536];  // K tile [64][1024B] / Vt tile [512][128B]
  __shared__ alignas(16) u16 sp[4096];               // S/P [64][64] bf16, XOR-swizzled
  __shared__ alignas(16) float mrun[64];
  __shared__ alignas(16) float lrun[64];
  __shared__ alignas(16) float alf[64];

  const int tid = threadIdx.x, lane = tid & 63, wv = tid >> 6;
  const int qs = wv >> 2, kg = wv & 3;
  const int bh = blockIdx.x & 31, qt = 15 - (blockIdx.x >> 5);
  const int b = bh >> 3, h = bh & 7;
  const char* const qkvb = (const char*)qkv;
  const char* const vtb = (const char*)vt;
  const f32x4 zero4 = {0.f, 0.f, 0.f, 0.f};

  if (tid < 64) { mrun[tid] = -3e38f; lrun[tid] = 0.f; }

  // per-wave Q row pointers (row frag mr=0 at qrow0, mr=1 at +16 rows)
  const char* qrow0;
  {
    const char* qbase = qkvb + ((size_t)(b * 1024 + qt * 64) * 12288 + h * 512) * 2;
    qrow0 = qbase + (size_t)(qs * 32 + (lane & 15)) * 24576 + (lane >> 4) * 16;
  }
  const char* qrow1 = qrow0 + (size_t)16 * 24576;

  f32x4 oacc[2][8];
#pragma unroll
  for (int mr = 0; mr < 2; ++mr)
#pragma unroll
    for (int dg = 0; dg < 8; ++dg) oacc[mr][dg] = zero4;

  const int ntiles = qt + 1;
  for (int t = 0; t < ntiles; ++t) {
    const int kv0 = t * 64;
    __syncthreads();  // prev PV reads / init visible before restaging
    {  // stage K tile (swizzled source -> linear LDS; read applies same XOR)
      const char* kbase = qkvb + ((size_t)(b * 1024 + kv0) * 12288 + 4096 + h * 512) * 2;
#pragma unroll
      for (int j = 0; j < 8; ++j) {
        const int c = wv * 8 + j;  // key row
        const unsigned w = (unsigned)(lane * 16) ^ ((c & 7) << 4);
        gl_lds16(kbase + (size_t)c * 24576 + w, kvb + c * 1024);
      }
    }
    __syncthreads();
    // S = Q @ K^T  (full 512-d reduction in-wave; wave owns 16 keys; Q from L1/L2)
    f32x4 sacc0 = zero4, sacc1 = zero4;
    {
      const int kr = kg * 16 + (lane & 15);
      const unsigned roff = (unsigned)kr * 1024u;
#pragma unroll
      for (int kk = 0; kk < 16; ++kk) {
        const s16x8 q0 = *(const s16x8*)(qrow0 + kk * 64);
        const s16x8 q1 = *(const s16x8*)(qrow1 + kk * 64);
        const s16x8 kf = *(const s16x8*)(kvb + roff +
            ((unsigned)(kk * 64 + (lane >> 4) * 16) ^ ((kr & 7) << 4)));
        sacc0 = mfma16(q0, kf, sacc0);
        sacc1 = mfma16(q1, kf, sacc1);
      }
    }
    {  // causal mask + store S (bf16, swizzled)
      const int col = kg * 16 + (lane & 15);
      const int kgl = kv0 + col;
#pragma unroll
      for (int mr = 0; mr < 2; ++mr)
#pragma unroll
        for (int i = 0; i < 4; ++i) {
          const int ql = qs * 32 + mr * 16 + (lane >> 4) * 4 + i;
          float s = (mr == 0) ? sacc0[i] : sacc1[i];
          if (kgl > qt * 64 + ql) s = -3e38f;
          *(u16*)((char*)sp + ql * 128 + ((unsigned)(col * 2) ^ ((ql & 7) << 4))) = f2bf(s);
        }
    }
    __syncthreads();
    {  // stage Vt tile (async; overlaps softmax below)
      const char* vbase = vtb + ((size_t)bh * 512 * 1024 + kv0) * 2;
#pragma unroll
      for (int j = 0; j < 8; ++j) {
        const int c = wv * 8 + j;
        const int d = c * 8 + (lane >> 3);
        const unsigned w = (unsigned)((lane & 7) * 16) ^ ((d & 7) << 4);
        gl_lds16(vbase + (size_t)d * 2048 + w, kvb + c * 1024);
      }
    }
    {  // online softmax: 8 lanes per row
      const int r = tid >> 3, sub = tid & 7;
      char* rowp = (char*)sp + r * 128;
      const unsigned off = (unsigned)(sub * 16) ^ ((r & 7) << 4);
      s16x8 sv = *(const s16x8*)(rowp + off);
      float sf[8];
#pragma unroll
      for (int j = 0; j < 8; ++j) sf[j] = bf2f((u16)sv[j]);
      float mt = sf[0];
#pragma unroll
      for (int j = 1; j < 8; ++j) mt = fmaxf(mt, sf[j]);
      mt = fmaxf(mt, __shfl_xor(mt, 1));
      mt = fmaxf(mt, __shfl_xor(mt, 2));
      mt = fmaxf(mt, __shfl_xor(mt, 4));
      const float mo = mrun[r];
      const float mn = fmaxf(mo, mt);
      float sum = 0.f;
      s16x8 pb;
#pragma unroll
      for (int j = 0; j < 8; ++j) {
        const float p = __expf(sf[j] - mn);
        sum += p;
        pb[j] = (short)f2bf(p);
      }
      *(s16x8*)(rowp + off) = pb;  // P in place of S
      sum += __shfl_xor(sum, 1);
      sum += __shfl_xor(sum, 2);
      sum += __shfl_xor(sum, 4);
      if (sub == 0) {
        const float a = __expf(mo - mn);
        alf[r] = a;
        lrun[r] = lrun[r] * a + sum;
        mrun[r] = mn;
      }
    }
    __syncthreads();
    // rescale O, then O += P @ V (wave owns 128-d slice d0 = kg*128)
#pragma unroll
    for (int mr = 0; mr < 2; ++mr) {
      const f32x4 a4 = *(const f32x4*)&alf[qs * 32 + mr * 16 + (lane >> 4) * 4];
#pragma unroll
      for (int dg = 0; dg < 8; ++dg) oacc[mr][dg] *= a4;
    }
    s16x8 pf[2][2];
#pragma unroll
    for (int mr = 0; mr < 2; ++mr) {
      const int q = qs * 32 + mr * 16 + (lane & 15);
#pragma unroll
      for (int k2 = 0; k2 < 2; ++k2)
        pf[mr][k2] = *(const s16x8*)((const char*)sp + q * 128 +
            ((unsigned)(k2 * 64 + (lane >> 4) * 16) ^ ((q & 7) << 4)));
    }
#pragma unroll
    for (int dg = 0; dg < 8; ++dg) {
      const int d = kg * 128 + dg * 16 + (lane & 15);
      const unsigned doff = (unsigned)d * 128u;
#pragma unroll
      for (int k2 = 0; k2 < 2; ++k2) {
        const s16x8 vf = *(const s16x8*)(kvb + doff +
            ((unsigned)(k2 * 64 + (lane >> 4) * 16) ^ ((d & 7) << 4)));
        oacc[0][dg] = mfma16(pf[0][k2], vf, oacc[0][dg]);
        oacc[1][dg] = mfma16(pf[1][k2], vf, oacc[1][dg]);
      }
    }
  }
  // normalize + write O tile (bf16)
#pragma unroll
  for (int mr = 0; mr < 2; ++mr) {
    const f32x4 l4 = *(const f32x4*)&lrun[qs * 32 + mr * 16 + (lane >> 4) * 4];
#pragma unroll
    for (int dg = 0; dg < 8; ++dg) {
      const int colo = h * 512 + kg * 128 + dg * 16 + (lane & 15);
#pragma unroll
      for (int i = 0; i < 4; ++i) {
        const int row = b * 1024 + qt * 64 + qs * 32 + mr * 16 + (lane >> 4) * 4 + i;
        O[(size_t)row * 4096 + colo] = f2bf(oacc[mr][dg][i] / l4[i]);
      }
    }
  }
}

// ---------------------------------------------------------------- launch
extern "C" void kernel_launch(void* const* d_in, const int* in_sizes, int n_in,
                              void* d_out, int out_size, void* d_ws, size_t ws_size,
                              hipStream_t stream) {
  (void)in_sizes; (void)n_in; (void)out_size; (void)ws_size;
  const float* x  = (const float*)d_in[0];
  const float* Wq = (const float*)d_in[1];
  const float* Wk = (const float*)d_in[2];
  const float* Wv = (const float*)d_in[3];
  const float* Wo = (const float*)d_in[4];
  const float* bo = (const float*)d_in[5];
  float* out = (float*)d_out;

  // workspace layout (u16 elements); total 188,743,680 bytes
  u16* ws   = (u16*)d_ws;
  u16* xb   = ws;                    // 4096*512
  u16* WT   = xb + 2097152;          // 12288*512  (WqT | WkT | WvT)
  u16* WoT  = WT + 6291456;          // 512*4096
  u16* QKV  = WoT + 2097152;         // 4096*12288
  u16* VT   = QKV + 50331648;        // 32*512*1024
  u16* Obuf = VT + 16777216;         // 4096*4096

  const float qscale = 0.044194173824159216f;  // 1/sqrt(512)

  k_cvt_x<<<2048, 256, 0, stream>>>((const float4*)x, xb, 524288);

  dim3 gw3(8, 64, 3);  // K/64=8, N/64=64, {Wq,Wk,Wv}
  k_transpose_w3<<<gw3, 256, 0, stream>>>(Wq, Wk, Wv, WT, qscale);
  dim3 gwo(64, 8);
  k_transpose_w<<<gwo, 256, 0, stream>>>(Wo, WoT, 4096, 512, 1.f);

  dim3 g1(96, 32);  // N/128, M/128
  k_gemm<128, 128, 0><<<g1, 256, 0, stream>>>(xb, WT, (void*)QKV, nullptr,
                                              4096, 12288, 512, 12288);

  dim3 gv(16, 8, 32);  // k-tiles, d-tiles, bh
  k_transpose_v<<<gv, 256, 0, stream>>>(QKV, VT);

  k_attn<<<512, 512, 0, stream>>>(QKV, VT, Obuf);

  dim3 g2(8, 32);  // N/64, M/128
  k_gemm<128, 64, 1><<<g2, 256, 0, stream>>>(Obuf, WoT, (void*)out, bo,
                                             4096, 512, 4096, 512);
}

// Round 3
// 464.697 us; speedup vs baseline: 1.2289x; 1.2289x over previous
//
#include <hip/hip_runtime.h>
#include <hip/hip_bf16.h>

typedef unsigned short u16;
typedef __attribute__((ext_vector_type(4))) float f32x4;
typedef __attribute__((ext_vector_type(8))) short s16x8;  // 8 x bf16 (4 VGPRs)
typedef __attribute__((ext_vector_type(4))) short s16x4;

#define DEVFN static __device__ __forceinline__

DEVFN u16 f2bf(float f) {  // fp32 -> bf16, round-nearest-even
  unsigned u = __float_as_uint(f);
  return (u16)((u + 0x7fffu + ((u >> 16) & 1u)) >> 16);
}
DEVFN float bf2f(u16 h) { return __uint_as_float(((unsigned)h) << 16); }

DEVFN void gl_lds16(const void* g, void* l) {  // async global->LDS, 16B/lane
  __builtin_amdgcn_global_load_lds(
      (const __attribute__((address_space(1))) unsigned int*)g,
      (__attribute__((address_space(3))) unsigned int*)l, 16, 0, 0);
}

DEVFN f32x4 mfma16(s16x8 a, s16x8 b, f32x4 c) {
  return __builtin_amdgcn_mfma_f32_16x16x32_bf16(a, b, c, 0, 0, 0);
}

// ---------------------------------------------------------------- cvt x -> bf16
__global__ void k_cvt_x(const float4* __restrict__ x, u16* __restrict__ xb, int n4) {
  int i = blockIdx.x * 256 + threadIdx.x;
  if (i >= n4) return;
  float4 v = x[i];
  s16x4 o;
  o[0] = (short)f2bf(v.x); o[1] = (short)f2bf(v.y);
  o[2] = (short)f2bf(v.z); o[3] = (short)f2bf(v.w);
  *(s16x4*)(xb + (size_t)i * 4) = o;
}

// ------------------------------------------- transpose+convert Wq/Wk/Wv (f32 512x4096 -> bf16 4096x512)
__global__ void k_transpose_w3(const float* __restrict__ Wq, const float* __restrict__ Wk,
                               const float* __restrict__ Wv, u16* __restrict__ dst,
                               float qscale) {
  __shared__ float tile[64][65];
  const int z = blockIdx.z;
  const float* src = (z == 0) ? Wq : (z == 1) ? Wk : Wv;
  const float scale = (z == 0) ? qscale : 1.f;
  u16* d = dst + (size_t)z * 2097152;
  int k0 = blockIdx.x * 64, n0 = blockIdx.y * 64;
  int t = threadIdx.x, c = t & 63, r4 = t >> 6;
#pragma unroll
  for (int i = 0; i < 16; ++i) {
    int r = i * 4 + r4;
    tile[r][c] = src[(size_t)(k0 + r) * 4096 + n0 + c] * scale;
  }
  __syncthreads();
#pragma unroll
  for (int i = 0; i < 16; ++i) {
    int r = i * 4 + r4;
    d[(size_t)(n0 + r) * 512 + k0 + c] = f2bf(tile[c][r]);
  }
}

// ------------------------------------------- transpose+convert Wo (f32 KxN -> bf16 NxK)
__global__ void k_transpose_w(const float* __restrict__ src, u16* __restrict__ dst,
                              int K, int N, float scale) {
  __shared__ float tile[64][65];
  int k0 = blockIdx.x * 64, n0 = blockIdx.y * 64;
  int t = threadIdx.x, c = t & 63, r4 = t >> 6;
#pragma unroll
  for (int i = 0; i < 16; ++i) {
    int r = i * 4 + r4;
    tile[r][c] = src[(size_t)(k0 + r) * N + n0 + c] * scale;
  }
  __syncthreads();
#pragma unroll
  for (int i = 0; i < 16; ++i) {
    int r = i * 4 + r4;
    dst[(size_t)(n0 + r) * K + k0 + c] = f2bf(tile[c][r]);
  }
}

// ------------------------------------------- transpose V region of QKV -> Vt [32][512][1024]
__global__ void k_transpose_v(const u16* __restrict__ qkv, u16* __restrict__ vt) {
  __shared__ u16 tile[64][65];
  int bh = blockIdx.z, b = bh >> 3, h = bh & 7;
  int kk0 = blockIdx.x * 64, d0 = blockIdx.y * 64;
  int t = threadIdx.x, c = t & 63, r4 = t >> 6;
#pragma unroll
  for (int i = 0; i < 16; ++i) {
    int r = i * 4 + r4;  // key-local
    tile[r][c] = qkv[(size_t)(b * 1024 + kk0 + r) * 12288 + 8192 + h * 512 + d0 + c];
  }
  __syncthreads();
#pragma unroll
  for (int i = 0; i < 16; ++i) {
    int r = i * 4 + r4;  // d-local
    vt[(size_t)(bh * 512 + d0 + r) * 1024 + kk0 + c] = tile[c][r];
  }
}

// ---------------------------------------------------------------- m97-style GEMM
// C[M][ldc] = A[M][K] @ Bt[N][K]^T   (A, Bt bf16 row-major; B^T layout)
// EPI 0: C bf16;  EPI 1: C f32 + bias
template <int BM, int BN, int EPI>
__global__ void __launch_bounds__(256, 2) k_gemm(
    const u16* __restrict__ A, const u16* __restrict__ Bt,
    void* __restrict__ Cp, const float* __restrict__ bias,
    int M, int N, int K, int ldc) {
  constexpr int MR = BM / 32, NR = BN / 32;      // frags per wave
  constexpr int CHA = BM / 16, CHB = BN / 16;    // 1KB staging chunks
  __shared__ alignas(16) u16 Alds[BM * 32];
  __shared__ alignas(16) u16 Blds[BN * 32];
  const int tid = threadIdx.x, lane = tid & 63, wv = tid >> 6;
  const int wr = wv >> 1, wc = wv & 1;
  const int row0 = blockIdx.y * BM, col0 = blockIdx.x * BN;
  const char* Ab = (const char*)A;
  const char* Bb = (const char*)Bt;
  const f32x4 zero4 = {0.f, 0.f, 0.f, 0.f};
  f32x4 acc[MR][NR];
#pragma unroll
  for (int m = 0; m < MR; ++m)
#pragma unroll
    for (int n = 0; n < NR; ++n) acc[m][n] = zero4;

  for (int k0 = 0; k0 < K; k0 += 32) {
#pragma unroll
    for (int j = 0; j < CHA / 4; ++j) {
      int ch = j * 4 + wv;
      int r = ch * 16 + (lane >> 2);
      int cb = (lane & 3) * 16;
      gl_lds16(Ab + ((size_t)(row0 + r) * K + k0) * 2 + cb, (char*)Alds + ch * 1024);
    }
#pragma unroll
    for (int j = 0; j < CHB / 4; ++j) {
      int ch = j * 4 + wv;
      int r = ch * 16 + (lane >> 2);
      int cb = (lane & 3) * 16;
      gl_lds16(Bb + ((size_t)(col0 + r) * K + k0) * 2 + cb, (char*)Blds + ch * 1024);
    }
    __syncthreads();
    s16x8 af[MR], bfr[NR];
#pragma unroll
    for (int m = 0; m < MR; ++m)
      af[m] = *(const s16x8*)((const char*)Alds +
               (wr * (BM / 2) + m * 16 + (lane & 15)) * 64 + (lane >> 4) * 16);
#pragma unroll
    for (int n = 0; n < NR; ++n)
      bfr[n] = *(const s16x8*)((const char*)Blds +
                (wc * (BN / 2) + n * 16 + (lane & 15)) * 64 + (lane >> 4) * 16);
#pragma unroll
    for (int m = 0; m < MR; ++m)
#pragma unroll
      for (int n = 0; n < NR; ++n) acc[m][n] = mfma16(af[m], bfr[n], acc[m][n]);
    __syncthreads();
  }
#pragma unroll
  for (int m = 0; m < MR; ++m)
#pragma unroll
    for (int n = 0; n < NR; ++n)
#pragma unroll
      for (int i = 0; i < 4; ++i) {
        int r = row0 + wr * (BM / 2) + m * 16 + (lane >> 4) * 4 + i;
        int c = col0 + wc * (BN / 2) + n * 16 + (lane & 15);
        if (EPI == 0)
          ((u16*)Cp)[(size_t)r * ldc + c] = f2bf(acc[m][n][i]);
        else
          ((float*)Cp)[(size_t)r * ldc + c] = acc[m][n][i] + bias[c];
      }
}

// ---------------------------------------------------------------- flash attention
// 256-thread blocks, QBLK=32, KVB=32; grid 1024 = 4 blocks/CU (LDS ~35KB, VGPR<=128).
// bh = bid&31 (a CU's 4 blocks share one head -> K/V L2-resident).
// g = bid>>5 mapped so each CU's quartet {u,31-u,15-u,16+u} sums to 62 tiles.
// 4 waves: qs = wv>>1 (16 q-rows), kg = wv&1 (16 keys in QK / 256-d slice in PV).
__global__ void __launch_bounds__(256, 4) k_attn(
    const u16* __restrict__ qkv, const u16* __restrict__ vt, u16* __restrict__ O) {
  __shared__ alignas(128) unsigned char kvb[32768];  // K tile [32][1024B] / Vt tile [512][64B]
  __shared__ alignas(16) u16 sp[1024];               // S/P [32][32] bf16, XOR-swizzled
  __shared__ alignas(16) float mrun[32];
  __shared__ alignas(16) float lrun[32];
  __shared__ alignas(16) float alf[32];

  const int tid = threadIdx.x, lane = tid & 63, wv = tid >> 6;
  const int qs = wv >> 1, kg = wv & 1;
  const int bh = blockIdx.x & 31;
  const int g = blockIdx.x >> 5, s = g >> 3, u = g & 7;
  const int qt = (s == 0) ? u : (s == 1) ? (31 - u) : (s == 2) ? (15 - u) : (16 + u);
  const int b = bh >> 3, h = bh & 7;
  const char* const qkvb = (const char*)qkv;
  const char* const vtb = (const char*)vt;
  const f32x4 zero4 = {0.f, 0.f, 0.f, 0.f};

  if (tid < 32) { mrun[tid] = -3e38f; lrun[tid] = 0.f; }

  // per-wave Q row pointer: rows qs*16..+16 of q-tile qt, streamed from L2 each tile
  const char* qrow;
  {
    const char* qbase = qkvb + ((size_t)(b * 1024 + qt * 32) * 12288 + h * 512) * 2;
    qrow = qbase + (size_t)(qs * 16 + (lane & 15)) * 24576 + (lane >> 4) * 16;
  }

  f32x4 oacc[16];  // wave owns [16 q] x [256 d]  (d0 = kg*256)
#pragma unroll
  for (int dg = 0; dg < 16; ++dg) oacc[dg] = zero4;

  const int ntiles = qt + 1;
  for (int t = 0; t < ntiles; ++t) {
    const int kv0 = t * 32;
    __syncthreads();  // prev PV reads / init visible before restaging
    {  // stage K tile: 32 rows x 1KB, source-swizzled (chunk l ^ (row&7))
      const char* kbase = qkvb + ((size_t)(b * 1024 + kv0) * 12288 + 4096 + h * 512) * 2;
#pragma unroll
      for (int j = 0; j < 8; ++j) {
        const int c = wv * 8 + j;  // key row
        const unsigned w = (unsigned)(lane * 16) ^ ((c & 7) << 4);
        gl_lds16(kbase + (size_t)c * 24576 + w, kvb + c * 1024);
      }
    }
    __syncthreads();
    // S = Q @ K^T  (full 512-d reduction; wave owns [16 q][16 k]; Q from L1/L2)
    f32x4 sacc = zero4;
    {
      const int kr = kg * 16 + (lane & 15);
      const unsigned roff = (unsigned)kr * 1024u;
#pragma unroll
      for (int kk = 0; kk < 16; ++kk) {
        const s16x8 q0 = *(const s16x8*)(qrow + kk * 64);
        const s16x8 kf = *(const s16x8*)(kvb + roff +
            ((unsigned)(kk * 64 + (lane >> 4) * 16) ^ ((kr & 7) << 4)));
        sacc = mfma16(q0, kf, sacc);
      }
    }
    {  // causal mask + store S (bf16, swizzled: byte ^ ((q&3)<<4))
      const int col = kg * 16 + (lane & 15);
      const int kgl = kv0 + col;
#pragma unroll
      for (int i = 0; i < 4; ++i) {
        const int ql = qs * 16 + (lane >> 4) * 4 + i;
        float sv = sacc[i];
        if (kgl > qt * 32 + ql) sv = -3e38f;
        *(u16*)((char*)sp + ql * 64 + ((unsigned)(col * 2) ^ ((ql & 3) << 4))) = f2bf(sv);
      }
    }
    __syncthreads();
    {  // stage Vt tile (async; overlaps softmax): [512 d][64B], src-swizzled
      const char* vbase = vtb + ((size_t)bh * 512 * 1024 + kv0) * 2;
#pragma unroll
      for (int j = 0; j < 8; ++j) {
        const int c = wv * 8 + j;                 // 1KB chunk = 16 d-rows
        const int d = c * 16 + (lane >> 2);
        const unsigned srcch = (unsigned)((lane & 3) ^ ((lane >> 2) & 3));
        gl_lds16(vbase + (size_t)d * 2048 + srcch * 16, kvb + c * 1024);
      }
    }
    {  // online softmax: 8 lanes per row, 4 elems each
      const int r = tid >> 3, sub = tid & 7;
      char* rowp = (char*)sp + r * 64;
      const unsigned off = (unsigned)(sub * 8) ^ ((r & 3) << 4);
      s16x4 svv = *(const s16x4*)(rowp + off);
      float sf[4];
#pragma unroll
      for (int j = 0; j < 4; ++j) sf[j] = bf2f((u16)svv[j]);
      float mt = fmaxf(fmaxf(sf[0], sf[1]), fmaxf(sf[2], sf[3]));
      mt = fmaxf(mt, __shfl_xor(mt, 1));
      mt = fmaxf(mt, __shfl_xor(mt, 2));
      mt = fmaxf(mt, __shfl_xor(mt, 4));
      const float mo = mrun[r];
      const float mn = fmaxf(mo, mt);
      float sum = 0.f;
      s16x4 pb;
#pragma unroll
      for (int j = 0; j < 4; ++j) {
        const float p = __expf(sf[j] - mn);
        sum += p;
        pb[j] = (short)f2bf(p);
      }
      *(s16x4*)(rowp + off) = pb;  // P in place of S
      sum += __shfl_xor(sum, 1);
      sum += __shfl_xor(sum, 2);
      sum += __shfl_xor(sum, 4);
      if (sub == 0) {
        const float a = __expf(mo - mn);
        alf[r] = a;
        lrun[r] = lrun[r] * a + sum;
        mrun[r] = mn;
      }
    }
    __syncthreads();
    // rescale O, then O += P @ V (wave owns 256-d slice d0 = kg*256; K=32 -> 1 mfma/tile)
    {
      const f32x4 a4 = *(const f32x4*)&alf[qs * 16 + (lane >> 4) * 4];
#pragma unroll
      for (int dg = 0; dg < 16; ++dg) oacc[dg] *= a4;
    }
    s16x8 pf;
    {
      const int q = qs * 16 + (lane & 15);
      pf = *(const s16x8*)((const char*)sp + q * 64 +
          ((unsigned)((lane >> 4) * 16) ^ ((q & 3) << 4)));
    }
#pragma unroll
    for (int dg = 0; dg < 16; ++dg) {
      const int d = kg * 256 + dg * 16 + (lane & 15);
      const s16x8 vf = *(const s16x8*)(kvb + (unsigned)d * 64u +
          ((unsigned)((lane >> 4) * 16) ^ ((d & 3) << 4)));
      oacc[dg] = mfma16(pf, vf, oacc[dg]);
    }
  }
  // normalize + write O tile (bf16)
  {
    const f32x4 l4 = *(const f32x4*)&lrun[qs * 16 + (lane >> 4) * 4];
#pragma unroll
    for (int dg = 0; dg < 16; ++dg) {
      const int colo = h * 512 + kg * 256 + dg * 16 + (lane & 15);
#pragma unroll
      for (int i = 0; i < 4; ++i) {
        const int row = b * 1024 + qt * 32 + qs * 16 + (lane >> 4) * 4 + i;
        O[(size_t)row * 4096 + colo] = f2bf(oacc[dg][i] / l4[i]);
      }
    }
  }
}

// ---------------------------------------------------------------- launch
extern "C" void kernel_launch(void* const* d_in, const int* in_sizes, int n_in,
                              void* d_out, int out_size, void* d_ws, size_t ws_size,
                              hipStream_t stream) {
  (void)in_sizes; (void)n_in; (void)out_size; (void)ws_size;
  const float* x  = (const float*)d_in[0];
  const float* Wq = (const float*)d_in[1];
  const float* Wk = (const float*)d_in[2];
  const float* Wv = (const float*)d_in[3];
  const float* Wo = (const float*)d_in[4];
  const float* bo = (const float*)d_in[5];
  float* out = (float*)d_out;

  // workspace layout (u16 elements); total 188,743,680 bytes
  u16* ws   = (u16*)d_ws;
  u16* xb   = ws;                    // 4096*512
  u16* WT   = xb + 2097152;          // 12288*512  (WqT | WkT | WvT)
  u16* WoT  = WT + 6291456;          // 512*4096
  u16* QKV  = WoT + 2097152;         // 4096*12288
  u16* VT   = QKV + 50331648;        // 32*512*1024
  u16* Obuf = VT + 16777216;         // 4096*4096

  const float qscale = 0.044194173824159216f;  // 1/sqrt(512)

  k_cvt_x<<<2048, 256, 0, stream>>>((const float4*)x, xb, 524288);

  dim3 gw3(8, 64, 3);  // K/64=8, N/64=64, {Wq,Wk,Wv}
  k_transpose_w3<<<gw3, 256, 0, stream>>>(Wq, Wk, Wv, WT, qscale);
  dim3 gwo(64, 8);
  k_transpose_w<<<gwo, 256, 0, stream>>>(Wo, WoT, 4096, 512, 1.f);

  dim3 g1(96, 32);  // N/128, M/128
  k_gemm<128, 128, 0><<<g1, 256, 0, stream>>>(xb, WT, (void*)QKV, nullptr,
                                              4096, 12288, 512, 12288);

  dim3 gv(16, 8, 32);  // k-tiles, d-tiles, bh
  k_transpose_v<<<gv, 256, 0, stream>>>(QKV, VT);

  k_attn<<<1024, 256, 0, stream>>>(QKV, VT, Obuf);

  dim3 g2(8, 32);  // N/64, M/128
  k_gemm<128, 64, 1><<<g2, 256, 0, stream>>>(Obuf, WoT, (void*)out, bo,
                                             4096, 512, 4096, 512);
}

// Round 4
// 295.160 us; speedup vs baseline: 1.9347x; 1.5744x over previous
//
#include <hip/hip_runtime.h>
#include <hip/hip_bf16.h>

typedef unsigned short u16;
typedef __attribute__((ext_vector_type(4))) float f32x4;
typedef __attribute__((ext_vector_type(8))) short s16x8;  // 8 x bf16 (4 VGPRs)
typedef __attribute__((ext_vector_type(4))) short s16x4;

#define DEVFN static __device__ __forceinline__

DEVFN u16 f2bf(float f) {  // fp32 -> bf16, round-nearest-even
  unsigned u = __float_as_uint(f);
  return (u16)((u + 0x7fffu + ((u >> 16) & 1u)) >> 16);
}
DEVFN float bf2f(u16 h) { return __uint_as_float(((unsigned)h) << 16); }

DEVFN void gl_lds16(const void* g, void* l) {  // async global->LDS, 16B/lane
  __builtin_amdgcn_global_load_lds(
      (const __attribute__((address_space(1))) unsigned int*)g,
      (__attribute__((address_space(3))) unsigned int*)l, 16, 0, 0);
}

DEVFN f32x4 mfma16(s16x8 a, s16x8 b, f32x4 c) {
  return __builtin_amdgcn_mfma_f32_16x16x32_bf16(a, b, c, 0, 0, 0);
}

// ---------------------------------------------------------------- cvt x -> bf16
__global__ void k_cvt_x(const float4* __restrict__ x, u16* __restrict__ xb, int n4) {
  int i = blockIdx.x * 256 + threadIdx.x;
  if (i >= n4) return;
  float4 v = x[i];
  s16x4 o;
  o[0] = (short)f2bf(v.x); o[1] = (short)f2bf(v.y);
  o[2] = (short)f2bf(v.z); o[3] = (short)f2bf(v.w);
  *(s16x4*)(xb + (size_t)i * 4) = o;
}

// ------------------------------------------- transpose+convert Wq/Wk/Wv (f32 512x4096 -> bf16 4096x512)
__global__ void k_transpose_w3(const float* __restrict__ Wq, const float* __restrict__ Wk,
                               const float* __restrict__ Wv, u16* __restrict__ dst,
                               float qscale) {
  __shared__ float tile[64][65];
  const int z = blockIdx.z;
  const float* src = (z == 0) ? Wq : (z == 1) ? Wk : Wv;
  const float scale = (z == 0) ? qscale : 1.f;
  u16* d = dst + (size_t)z * 2097152;
  int k0 = blockIdx.x * 64, n0 = blockIdx.y * 64;
  int t = threadIdx.x, c = t & 63, r4 = t >> 6;
#pragma unroll
  for (int i = 0; i < 16; ++i) {
    int r = i * 4 + r4;
    tile[r][c] = src[(size_t)(k0 + r) * 4096 + n0 + c] * scale;
  }
  __syncthreads();
#pragma unroll
  for (int i = 0; i < 16; ++i) {
    int r = i * 4 + r4;
    d[(size_t)(n0 + r) * 512 + k0 + c] = f2bf(tile[c][r]);
  }
}

// ------------------------------------------- transpose+convert Wo (f32 KxN -> bf16 NxK)
__global__ void k_transpose_w(const float* __restrict__ src, u16* __restrict__ dst,
                              int K, int N, float scale) {
  __shared__ float tile[64][65];
  int k0 = blockIdx.x * 64, n0 = blockIdx.y * 64;
  int t = threadIdx.x, c = t & 63, r4 = t >> 6;
#pragma unroll
  for (int i = 0; i < 16; ++i) {
    int r = i * 4 + r4;
    tile[r][c] = src[(size_t)(k0 + r) * N + n0 + c] * scale;
  }
  __syncthreads();
#pragma unroll
  for (int i = 0; i < 16; ++i) {
    int r = i * 4 + r4;
    dst[(size_t)(n0 + r) * K + k0 + c] = f2bf(tile[c][r]);
  }
}

// ------------------------------------------- transpose V ([4096][4096] -> Vt [32][512][1024])
__global__ void k_transpose_v(const u16* __restrict__ vb, u16* __restrict__ vt) {
  __shared__ u16 tile[64][65];
  int bh = blockIdx.z, b = bh >> 3, h = bh & 7;
  int kk0 = blockIdx.x * 64, d0 = blockIdx.y * 64;
  int t = threadIdx.x, c = t & 63, r4 = t >> 6;
#pragma unroll
  for (int i = 0; i < 16; ++i) {
    int r = i * 4 + r4;  // key-local
    tile[r][c] = vb[(size_t)(b * 1024 + kk0 + r) * 4096 + h * 512 + d0 + c];
  }
  __syncthreads();
#pragma unroll
  for (int i = 0; i < 16; ++i) {
    int r = i * 4 + r4;  // d-local
    vt[(size_t)(bh * 512 + d0 + r) * 1024 + kk0 + c] = tile[c][r];
  }
}

// ---------------------------------------------------------------- m97-style batched GEMM
// C[.][ldc] = A[.][lda] @ Bt[.][ldb]^T   (bf16, B^T layout); batch via blockIdx.z:
// base += (z>>3)*s?b + (z&7)*s?h   (set s?b = 8*s?h for a linear-in-z stride).
// EPI 0: C bf16;  EPI 1: C f32 + bias.  CAUSAL: skip blocks with x>y (S lower triangle).
// VARK: K_eff = (blockIdx.y+1)*BM  (P@V: q-tile qt only needs keys < (qt+1)*128).
template <int BM, int BN, int EPI, int CAUSAL, int VARK>
__global__ void __launch_bounds__(256, 2) k_gemm(
    const u16* __restrict__ A, const u16* __restrict__ Bt,
    void* __restrict__ Cp, const float* __restrict__ bias,
    int K, int lda, int ldb, int ldc,
    size_t sAb, size_t sAh, size_t sBb, size_t sBh, size_t sCb, size_t sCh) {
  if (CAUSAL && blockIdx.x > blockIdx.y) return;
  constexpr int MR = BM / 32, NR = BN / 32;      // frags per wave
  constexpr int CHA = BM / 16, CHB = BN / 16;    // 1KB staging chunks
  __shared__ alignas(16) u16 Alds[BM * 32];
  __shared__ alignas(16) u16 Blds[BN * 32];
  const int tid = threadIdx.x, lane = tid & 63, wv = tid >> 6;
  const int wr = wv >> 1, wc = wv & 1;
  const int row0 = blockIdx.y * BM, col0 = blockIdx.x * BN;
  const int zb = blockIdx.z >> 3, zh = blockIdx.z & 7;
  const char* Ab = (const char*)(A + (size_t)zb * sAb + (size_t)zh * sAh);
  const char* Bb = (const char*)(Bt + (size_t)zb * sBb + (size_t)zh * sBh);
  const size_t coff = (size_t)zb * sCb + (size_t)zh * sCh;
  const int Klim = VARK ? (blockIdx.y + 1) * BM : K;
  const f32x4 zero4 = {0.f, 0.f, 0.f, 0.f};
  f32x4 acc[MR][NR];
#pragma unroll
  for (int m = 0; m < MR; ++m)
#pragma unroll
    for (int n = 0; n < NR; ++n) acc[m][n] = zero4;

  for (int k0 = 0; k0 < Klim; k0 += 32) {
#pragma unroll
    for (int j = 0; j < CHA / 4; ++j) {
      int ch = j * 4 + wv;
      int r = ch * 16 + (lane >> 2);
      int cb = (lane & 3) * 16;
      gl_lds16(Ab + ((size_t)(row0 + r) * lda + k0) * 2 + cb, (char*)Alds + ch * 1024);
    }
#pragma unroll
    for (int j = 0; j < CHB / 4; ++j) {
      int ch = j * 4 + wv;
      int r = ch * 16 + (lane >> 2);
      int cb = (lane & 3) * 16;
      gl_lds16(Bb + ((size_t)(col0 + r) * ldb + k0) * 2 + cb, (char*)Blds + ch * 1024);
    }
    __syncthreads();
    s16x8 af[MR], bfr[NR];
#pragma unroll
    for (int m = 0; m < MR; ++m)
      af[m] = *(const s16x8*)((const char*)Alds +
               (wr * (BM / 2) + m * 16 + (lane & 15)) * 64 + (lane >> 4) * 16);
#pragma unroll
    for (int n = 0; n < NR; ++n)
      bfr[n] = *(const s16x8*)((const char*)Blds +
                (wc * (BN / 2) + n * 16 + (lane & 15)) * 64 + (lane >> 4) * 16);
#pragma unroll
    for (int m = 0; m < MR; ++m)
#pragma unroll
      for (int n = 0; n < NR; ++n) acc[m][n] = mfma16(af[m], bfr[n], acc[m][n]);
    __syncthreads();
  }
#pragma unroll
  for (int m = 0; m < MR; ++m)
#pragma unroll
    for (int n = 0; n < NR; ++n)
#pragma unroll
      for (int i = 0; i < 4; ++i) {
        int r = row0 + wr * (BM / 2) + m * 16 + (lane >> 4) * 4 + i;
        int c = col0 + wc * (BN / 2) + n * 16 + (lane & 15);
        if (EPI == 0)
          ((u16*)Cp)[coff + (size_t)r * ldc + c] = f2bf(acc[m][n][i]);
        else
          ((float*)Cp)[coff + (size_t)r * ldc + c] = acc[m][n][i] + bias[c];
      }
}

// ---------------------------------------------------------------- causal row softmax
// S = [32 bh][1024 q][1024 k] bf16. One wave per row (16 cols/lane, fully static).
// Masks by column index (k > q -> 0), so the GEMM never masks; unwritten upper
// tiles are read but discarded. Writes the full normalized row.
__global__ void __launch_bounds__(256) k_softmax(u16* __restrict__ S) {
  const int tid = threadIdx.x, lane = tid & 63, w = tid >> 6;
  const int row = blockIdx.x * 4 + w;
  const int q = row & 1023;
  u16* rowp = S + (size_t)(row >> 10) * 1048576 + (size_t)(row & 1023) * 1024;
  const int c0 = lane * 8, c1 = 512 + lane * 8;
  s16x8 v0 = *(const s16x8*)(rowp + c0);
  s16x8 v1 = *(const s16x8*)(rowp + c1);
  float f[16];
#pragma unroll
  for (int j = 0; j < 8; ++j) {
    f[j]     = (c0 + j <= q) ? bf2f((u16)v0[j]) : -3e38f;
    f[8 + j] = (c1 + j <= q) ? bf2f((u16)v1[j]) : -3e38f;
  }
  float m = f[0];
#pragma unroll
  for (int j = 1; j < 16; ++j) m = fmaxf(m, f[j]);
  m = fmaxf(m, __shfl_xor(m, 1));
  m = fmaxf(m, __shfl_xor(m, 2));
  m = fmaxf(m, __shfl_xor(m, 4));
  m = fmaxf(m, __shfl_xor(m, 8));
  m = fmaxf(m, __shfl_xor(m, 16));
  m = fmaxf(m, __shfl_xor(m, 32));
  float sum = 0.f;
#pragma unroll
  for (int j = 0; j < 16; ++j) { f[j] = __expf(f[j] - m); sum += f[j]; }
  sum += __shfl_xor(sum, 1);
  sum += __shfl_xor(sum, 2);
  sum += __shfl_xor(sum, 4);
  sum += __shfl_xor(sum, 8);
  sum += __shfl_xor(sum, 16);
  sum += __shfl_xor(sum, 32);
  const float inv = 1.f / sum;  // sum >= 1 (diagonal term)
#pragma unroll
  for (int j = 0; j < 8; ++j) {
    v0[j] = (short)f2bf(f[j] * inv);
    v1[j] = (short)f2bf(f[8 + j] * inv);
  }
  *(s16x8*)(rowp + c0) = v0;
  *(s16x8*)(rowp + c1) = v1;
}

// ---------------------------------------------------------------- launch
// Workspace aliasing plan (MB offsets; peak live 164 MB < proven 188.7 MB):
//   [0,4)    WoT        (live: setup -> final GEMM)
//   [4,36)   Qb         (steps 3-5)  == Obuf (steps 7-8)
//   [36,68)  Kb         (steps 3-5)
//   [68,132) S          (steps 5-7); first half == Vb (steps 3-4)
//   [132,164) VT        (steps 4-7); overlays xb[132,136)+WT[136,148) (dead after step 3)
extern "C" void kernel_launch(void* const* d_in, const int* in_sizes, int n_in,
                              void* d_out, int out_size, void* d_ws, size_t ws_size,
                              hipStream_t stream) {
  (void)in_sizes; (void)n_in; (void)out_size; (void)ws_size;
  const float* x  = (const float*)d_in[0];
  const float* Wq = (const float*)d_in[1];
  const float* Wk = (const float*)d_in[2];
  const float* Wv = (const float*)d_in[3];
  const float* Wo = (const float*)d_in[4];
  const float* bo = (const float*)d_in[5];
  float* out = (float*)d_out;

  u16* ws   = (u16*)d_ws;
  u16* WoT  = ws;                    // 512*4096            [0,4) MB
  u16* Qb   = ws + 2097152;          // 4096*4096           [4,36)
  u16* Obuf = Qb;                    //                     (alias, later)
  u16* Kb   = ws + 18874368;         // 4096*4096           [36,68)
  u16* S    = ws + 35651584;         // 32*1024*1024        [68,132)
  u16* Vb   = S;                     // 4096*4096           (alias, earlier)
  u16* xb   = ws + 69206016;         // 4096*512            [132,136)
  u16* WT   = ws + 71303168;         // 3*4096*512          [136,148)
  u16* VT   = ws + 69206016;         // 32*512*1024         [132,164) (overlays xb,WT)

  const float qscale = 0.044194173824159216f;  // 1/sqrt(512)

  // 1-2: convert inputs
  k_cvt_x<<<2048, 256, 0, stream>>>((const float4*)x, xb, 524288);
  dim3 gw3(8, 64, 3);
  k_transpose_w3<<<gw3, 256, 0, stream>>>(Wq, Wk, Wv, WT, qscale);
  dim3 gwo(64, 8);
  k_transpose_w<<<gwo, 256, 0, stream>>>(Wo, WoT, 4096, 512, 1.f);

  // 3: Q/K/V projections (M=4096, N=4096, K=512 each)
  dim3 gp(32, 32, 1);
  k_gemm<128, 128, 0, 0, 0><<<gp, 256, 0, stream>>>(xb, WT, (void*)Qb, nullptr,
      512, 512, 512, 4096, 0, 0, 0, 0, 0, 0);
  k_gemm<128, 128, 0, 0, 0><<<gp, 256, 0, stream>>>(xb, WT + 2097152, (void*)Kb, nullptr,
      512, 512, 512, 4096, 0, 0, 0, 0, 0, 0);
  k_gemm<128, 128, 0, 0, 0><<<gp, 256, 0, stream>>>(xb, WT + 4194304, (void*)Vb, nullptr,
      512, 512, 512, 4096, 0, 0, 0, 0, 0, 0);

  // 4: V -> Vt [bh][512][1024]
  dim3 gv(16, 8, 32);
  k_transpose_v<<<gv, 256, 0, stream>>>(Vb, VT);

  // 5: S = Q @ K^T, causal lower-triangle tiles only (batched over 32 bh)
  dim3 g1(8, 8, 32);
  k_gemm<128, 128, 0, 1, 0><<<g1, 256, 0, stream>>>(Qb, Kb, (void*)S, nullptr,
      512, 4096, 4096, 1024,
      4194304, 512, 4194304, 512, 8388608, 1048576);

  // 6: causal softmax over S rows
  k_softmax<<<8192, 256, 0, stream>>>(S);

  // 7: Obuf = P @ V (variable-K: q-tile qt uses (qt+1)*128 keys)
  dim3 g2(4, 8, 32);
  k_gemm<128, 128, 0, 0, 1><<<g2, 256, 0, stream>>>(S, VT, (void*)Obuf, nullptr,
      1024, 1024, 1024, 4096,
      8388608, 1048576, 4194304, 524288, 4194304, 512);

  // 8: out = Obuf @ Wo + bo
  dim3 g3(8, 32, 1);
  k_gemm<128, 64, 1, 0, 0><<<g3, 256, 0, stream>>>(Obuf, WoT, (void*)out, bo,
      4096, 4096, 4096, 512, 0, 0, 0, 0, 0, 0);
}

// Round 5
// 236.444 us; speedup vs baseline: 2.4151x; 1.2483x over previous
//
#include <hip/hip_runtime.h>
#include <hip/hip_bf16.h>

typedef unsigned short u16;
typedef __attribute__((ext_vector_type(4))) float f32x4;
typedef __attribute__((ext_vector_type(8))) short s16x8;  // 8 x bf16 (4 VGPRs)
typedef __attribute__((ext_vector_type(4))) short s16x4;

#define DEVFN static __device__ __forceinline__

DEVFN u16 f2bf(float f) {  // fp32 -> bf16, round-nearest-even
  unsigned u = __float_as_uint(f);
  return (u16)((u + 0x7fffu + ((u >> 16) & 1u)) >> 16);
}
DEVFN float bf2f(u16 h) { return __uint_as_float(((unsigned)h) << 16); }

DEVFN void gl_lds16(const void* g, void* l) {  // async global->LDS, 16B/lane
  __builtin_amdgcn_global_load_lds(
      (const __attribute__((address_space(1))) unsigned int*)g,
      (__attribute__((address_space(3))) unsigned int*)l, 16, 0, 0);
}

DEVFN f32x4 mfma16(s16x8 a, s16x8 b, f32x4 c) {
  return __builtin_amdgcn_mfma_f32_16x16x32_bf16(a, b, c, 0, 0, 0);
}

// ---------------------------------------------------------------- cvt f32 -> bf16 (+scale)
__global__ void k_cvt(const float4* __restrict__ src, u16* __restrict__ dst,
                      float scale, int n4) {
  int i = blockIdx.x * 256 + threadIdx.x;
  if (i >= n4) return;
  float4 v = src[i];
  s16x4 o;
  o[0] = (short)f2bf(v.x * scale); o[1] = (short)f2bf(v.y * scale);
  o[2] = (short)f2bf(v.z * scale); o[3] = (short)f2bf(v.w * scale);
  *(s16x4*)(dst + (size_t)i * 4) = o;
}

// ------------------------------------------- transpose+convert Wo (f32 KxN -> bf16 NxK)
__global__ void k_transpose_w(const float* __restrict__ src, u16* __restrict__ dst,
                              int K, int N) {
  __shared__ float tile[64][65];
  int k0 = blockIdx.x * 64, n0 = blockIdx.y * 64;
  int t = threadIdx.x, c = t & 63, r4 = t >> 6;
#pragma unroll
  for (int i = 0; i < 16; ++i) {
    int r = i * 4 + r4;
    tile[r][c] = src[(size_t)(k0 + r) * N + n0 + c];
  }
  __syncthreads();
#pragma unroll
  for (int i = 0; i < 16; ++i) {
    int r = i * 4 + r4;
    dst[(size_t)(n0 + r) * K + k0 + c] = f2bf(tile[c][r]);
  }
}

// ------------------------------------------- transpose xb (bf16 [4][1024][512] -> xT [4][512][1024])
__global__ void k_transpose_x(const u16* __restrict__ xb, u16* __restrict__ xT) {
  __shared__ u16 tile[64][65];
  const int bz = blockIdx.z;
  const int r0 = blockIdx.x * 64, c0 = blockIdx.y * 64;
  int t = threadIdx.x, c = t & 63, r4 = t >> 6;
#pragma unroll
  for (int i = 0; i < 16; ++i) {
    int r = i * 4 + r4;
    tile[r][c] = xb[(size_t)(bz * 1024 + r0 + r) * 512 + c0 + c];
  }
  __syncthreads();
#pragma unroll
  for (int i = 0; i < 16; ++i) {
    int r = i * 4 + r4;
    xT[(size_t)bz * 524288 + (size_t)(c0 + r) * 1024 + r0 + c] = tile[c][r];
  }
}

// ---------------------------------------------------------------- m97-style batched GEMM
// C[.][ldc] = A[.][lda] @ Bt[.][ldb]^T  (bf16 in, B^T layout). Batch via blockIdx.z:
// offset += (z>>3)*s?b + (z&7)*s?h  (element strides; also reusable as k-chunk offsets
// for split-K by pointing sAh/sBh within a row and sCh at an fp32 partial plane).
// EPI 0: C bf16;  EPI 1: C f32 + bias;  EPI 2: C f32 raw (split-K partial).
// CAUSAL: skip tiles with x>y.  VARK: K_eff=(blockIdx.y+1)*BM.
template <int BM, int BN, int EPI, int CAUSAL, int VARK>
__global__ void __launch_bounds__(256, 2) k_gemm(
    const u16* __restrict__ A, const u16* __restrict__ Bt,
    void* __restrict__ Cp, const float* __restrict__ bias,
    int K, int lda, int ldb, int ldc,
    size_t sAb, size_t sAh, size_t sBb, size_t sBh, size_t sCb, size_t sCh) {
  if (CAUSAL && blockIdx.x > blockIdx.y) return;
  constexpr int MR = BM / 32, NR = BN / 32;      // frags per wave
  constexpr int CHA = BM / 16, CHB = BN / 16;    // 1KB staging chunks
  __shared__ alignas(16) u16 Alds[BM * 32];
  __shared__ alignas(16) u16 Blds[BN * 32];
  const int tid = threadIdx.x, lane = tid & 63, wv = tid >> 6;
  const int wr = wv >> 1, wc = wv & 1;
  const int row0 = blockIdx.y * BM, col0 = blockIdx.x * BN;
  const int zb = blockIdx.z >> 3, zh = blockIdx.z & 7;
  const char* Ab = (const char*)(A + (size_t)zb * sAb + (size_t)zh * sAh);
  const char* Bb = (const char*)(Bt + (size_t)zb * sBb + (size_t)zh * sBh);
  const size_t coff = (size_t)zb * sCb + (size_t)zh * sCh;
  const int Klim = VARK ? (blockIdx.y + 1) * BM : K;
  const f32x4 zero4 = {0.f, 0.f, 0.f, 0.f};
  f32x4 acc[MR][NR];
#pragma unroll
  for (int m = 0; m < MR; ++m)
#pragma unroll
    for (int n = 0; n < NR; ++n) acc[m][n] = zero4;

  for (int k0 = 0; k0 < Klim; k0 += 32) {
#pragma unroll
    for (int j = 0; j < CHA / 4; ++j) {
      int ch = j * 4 + wv;
      int r = ch * 16 + (lane >> 2);
      int cb = (lane & 3) * 16;
      gl_lds16(Ab + ((size_t)(row0 + r) * lda + k0) * 2 + cb, (char*)Alds + ch * 1024);
    }
#pragma unroll
    for (int j = 0; j < CHB / 4; ++j) {
      int ch = j * 4 + wv;
      int r = ch * 16 + (lane >> 2);
      int cb = (lane & 3) * 16;
      gl_lds16(Bb + ((size_t)(col0 + r) * ldb + k0) * 2 + cb, (char*)Blds + ch * 1024);
    }
    __syncthreads();
    s16x8 af[MR], bfr[NR];
#pragma unroll
    for (int m = 0; m < MR; ++m)
      af[m] = *(const s16x8*)((const char*)Alds +
               (wr * (BM / 2) + m * 16 + (lane & 15)) * 64 + (lane >> 4) * 16);
#pragma unroll
    for (int n = 0; n < NR; ++n)
      bfr[n] = *(const s16x8*)((const char*)Blds +
                (wc * (BN / 2) + n * 16 + (lane & 15)) * 64 + (lane >> 4) * 16);
#pragma unroll
    for (int m = 0; m < MR; ++m)
#pragma unroll
      for (int n = 0; n < NR; ++n) acc[m][n] = mfma16(af[m], bfr[n], acc[m][n]);
    __syncthreads();
  }
#pragma unroll
  for (int m = 0; m < MR; ++m)
#pragma unroll
    for (int n = 0; n < NR; ++n)
#pragma unroll
      for (int i = 0; i < 4; ++i) {
        int r = row0 + wr * (BM / 2) + m * 16 + (lane >> 4) * 4 + i;
        int c = col0 + wc * (BN / 2) + n * 16 + (lane & 15);
        if (EPI == 0)
          ((u16*)Cp)[coff + (size_t)r * ldc + c] = f2bf(acc[m][n][i]);
        else if (EPI == 1)
          ((float*)Cp)[coff + (size_t)r * ldc + c] = acc[m][n][i] + bias[c];
        else
          ((float*)Cp)[coff + (size_t)r * ldc + c] = acc[m][n][i];
      }
}

// ---------------------------------------------------------------- causal row softmax
// S = [32 bh][1024 q][1024 k] bf16. One wave per row; masks by column index.
// Rows q<512 touch only the first 512 columns (PV's VARK never reads beyond).
__global__ void __launch_bounds__(256) k_softmax(u16* __restrict__ S) {
  const int tid = threadIdx.x, lane = tid & 63, w = tid >> 6;
  const int row = blockIdx.x * 4 + w;
  const int q = row & 1023;
  u16* rowp = S + (size_t)(row >> 10) * 1048576 + (size_t)q * 1024;
  const int c0 = lane * 8, c1 = 512 + lane * 8;
  const bool hi = (q >= 512);
  s16x8 v0 = *(const s16x8*)(rowp + c0);
  s16x8 v1 = {};
  if (hi) v1 = *(const s16x8*)(rowp + c1);
  float f[16];
#pragma unroll
  for (int j = 0; j < 8; ++j) {
    f[j]     = (c0 + j <= q)       ? bf2f((u16)v0[j]) : -3e38f;
    f[8 + j] = (hi && c1 + j <= q) ? bf2f((u16)v1[j]) : -3e38f;
  }
  float m = f[0];
#pragma unroll
  for (int j = 1; j < 16; ++j) m = fmaxf(m, f[j]);
  m = fmaxf(m, __shfl_xor(m, 1));
  m = fmaxf(m, __shfl_xor(m, 2));
  m = fmaxf(m, __shfl_xor(m, 4));
  m = fmaxf(m, __shfl_xor(m, 8));
  m = fmaxf(m, __shfl_xor(m, 16));
  m = fmaxf(m, __shfl_xor(m, 32));
  float sum = 0.f;
#pragma unroll
  for (int j = 0; j < 16; ++j) { f[j] = __expf(f[j] - m); sum += f[j]; }
  sum += __shfl_xor(sum, 1);
  sum += __shfl_xor(sum, 2);
  sum += __shfl_xor(sum, 4);
  sum += __shfl_xor(sum, 8);
  sum += __shfl_xor(sum, 16);
  sum += __shfl_xor(sum, 32);
  const float inv = 1.f / sum;  // sum >= 1 (diagonal term)
#pragma unroll
  for (int j = 0; j < 8; ++j) {
    v0[j] = (short)f2bf(f[j] * inv);
    v1[j] = (short)f2bf(f[8 + j] * inv);
  }
  *(s16x8*)(rowp + c0) = v0;
  if (hi) *(s16x8*)(rowp + c1) = v1;
}

// ---------------------------------------------------------------- split-K reduce (+bias)
__global__ void k_reduce4(const float4* __restrict__ P, const float4* __restrict__ bias,
                          float4* __restrict__ out, int n4) {
  int i = blockIdx.x * 256 + threadIdx.x;
  if (i >= n4) return;
  float4 a = P[i], b = P[i + 524288], c = P[i + 1048576], d = P[i + 1572864];
  float4 bb = bias[i & 127];  // 512 cols / 4 = 128 float4 per row
  float4 o;
  o.x = a.x + b.x + c.x + d.x + bb.x;
  o.y = a.y + b.y + c.y + d.y + bb.y;
  o.z = a.z + b.z + c.z + d.z + bb.z;
  o.w = a.w + b.w + c.w + d.w + bb.w;
  out[i] = o;
}

// ---------------------------------------------------------------- launch
// Head-factored pipeline: G_h = Wq̂_h Wk_h^T, Wvo_h = Wv_h Wo_h (512² each) fold the
// K/V projections into the small per-head weight products:
//   y = x @ G^T   ->  S = y @ x^T (causal)  ->  softmax  ->
//   Z = P @ x     ->  out = Z @ WvoT^T + bo (split-K=4 + reduce)
// Workspace (u16 elems; 160 MB total, ws proven >= 188 MB):
//   xb 0 | xT 2M | Wqb 4M | Wkb 6M | Wvb 8M | WoT 10M | G 12M | WvoT 14M
//   y 16M..32M (32MB)  [aliased later by fp32 split-K partials]
//   S 32M..64M (64MB) | Z 64M..80M (32MB)
extern "C" void kernel_launch(void* const* d_in, const int* in_sizes, int n_in,
                              void* d_out, int out_size, void* d_ws, size_t ws_size,
                              hipStream_t stream) {
  (void)in_sizes; (void)n_in; (void)out_size; (void)ws_size;
  const float* x  = (const float*)d_in[0];
  const float* Wq = (const float*)d_in[1];
  const float* Wk = (const float*)d_in[2];
  const float* Wv = (const float*)d_in[3];
  const float* Wo = (const float*)d_in[4];
  const float* bo = (const float*)d_in[5];
  float* out = (float*)d_out;

  u16* ws   = (u16*)d_ws;
  u16* xb   = ws;                      // [4096][512]
  u16* xT   = ws + 2097152;            // [4][512][1024]
  u16* Wqb  = ws + 4194304;            // [512][4096] (scaled by 1/sqrt(512))
  u16* Wkb  = ws + 6291456;            // [512][4096]
  u16* Wvb  = ws + 8388608;            // [512][4096]
  u16* WoT  = ws + 10485760;           // [512][4096]
  u16* G    = ws + 12582912;           // [8][512][512]  G_h[e'][e] = sum_i Wk[e'][i]*Wq̂[e][i]
  u16* WvoT = ws + 14680064;           // [512][4096]    WvoT[c][h*512+e]
  u16* y    = ws + 16777216;           // [8][4096][512]
  u16* S    = ws + 33554432;           // [32][1024][1024]
  u16* Z    = ws + 67108864;           // [4096][4096]
  float* Pp = (float*)(ws + 16777216); // 4 x [4096][512] fp32 split-K partials (alias y)

  const float qscale = 0.044194173824159216f;  // 1/sqrt(512)

  // ---- prologue: converts & transposes
  k_cvt<<<2048, 256, 0, stream>>>((const float4*)x,  xb,  1.f,    524288);
  k_cvt<<<2048, 256, 0, stream>>>((const float4*)Wq, Wqb, qscale, 524288);
  k_cvt<<<2048, 256, 0, stream>>>((const float4*)Wk, Wkb, 1.f,    524288);
  k_cvt<<<2048, 256, 0, stream>>>((const float4*)Wv, Wvb, 1.f,    524288);
  k_transpose_w<<<dim3(64, 8), 256, 0, stream>>>(Wo, WoT, 4096, 512);
  k_transpose_x<<<dim3(16, 8, 4), 256, 0, stream>>>(xb, xT);

  // ---- per-head weight products (tiny)
  // G_h = Wk_h @ Wq̂_h^T  (rows e', cols e)
  k_gemm<64, 64, 0, 0, 0><<<dim3(8, 8, 8), 256, 0, stream>>>(
      Wkb, Wqb, (void*)G, nullptr, 512, 4096, 4096, 512,
      0, 512, 0, 512, 0, 262144);
  // WvoT[c][h*512+e] = sum_d WoT[c][h*512+d] * Wvb[e][h*512+d]
  k_gemm<64, 64, 0, 0, 0><<<dim3(8, 8, 8), 256, 0, stream>>>(
      WoT, Wvb, (void*)WvoT, nullptr, 512, 4096, 4096, 4096,
      0, 512, 0, 512, 0, 512);

  // ---- y_h = x @ G_h^T   [8][4096][512]
  k_gemm<128, 128, 0, 0, 0><<<dim3(4, 32, 8), 256, 0, stream>>>(
      xb, G, (void*)y, nullptr, 512, 512, 512, 512,
      0, 0, 0, 262144, 0, 2097152);

  // ---- S = y_h @ x_b^T  (causal lower-triangle tiles), batched over 32 bh
  k_gemm<128, 128, 0, 1, 0><<<dim3(8, 8, 32), 256, 0, stream>>>(
      y, xb, (void*)S, nullptr, 512, 512, 512, 1024,
      524288, 2097152, 524288, 0, 8388608, 1048576);

  // ---- causal softmax
  k_softmax<<<8192, 256, 0, stream>>>(S);

  // ---- Z = P @ x_b  (VARK: q-tile qt uses (qt+1)*128 keys)   [4096][4096]
  k_gemm<128, 128, 0, 0, 1><<<dim3(4, 8, 32), 256, 0, stream>>>(
      S, xT, (void*)Z, nullptr, 1024, 1024, 1024, 4096,
      8388608, 1048576, 524288, 0, 4194304, 512);

  // ---- out = Z @ WvoT^T + bo, split-K=4 (z = k-chunk via stride trick)
  k_gemm<128, 64, 2, 0, 0><<<dim3(8, 32, 4), 256, 0, stream>>>(
      Z, WvoT, (void*)Pp, nullptr, 1024, 4096, 4096, 512,
      0, 1024, 0, 1024, 0, 2097152);
  k_reduce4<<<2048, 256, 0, stream>>>((const float4*)Pp, (const float4*)bo,
                                      (float4*)out, 524288);
}